// Round 2
// baseline (2013.358 us; speedup 1.0000x reference)
//
#include <hip/hip_runtime.h>
#include <hip/hip_bf16.h>

#define N_NODES 50000
#define E_EDGES 800000
#define F_DIM 128
#define D_DIM 32
#define CUTOFF 5.0f

__device__ __forceinline__ float swishf(float x) { return x / (1.0f + expf(-x)); }

// ---------------------------------------------------------------------------
// Node MLP: q = swish(swish(x@W1+b1)@W2+b2), x:[N,128] f32, W1:[128,128],
// W2:[128,32]. One wave per row; W1 staged in LDS one 64-col half at a time
// (32 KB), W2 resident (16 KB). sX/sH are wave-private (no barriers needed).
// ---------------------------------------------------------------------------
__global__ __launch_bounds__(512)
void node_mlp(const float* __restrict__ x,
              const float* __restrict__ W1, const float* __restrict__ b1,
              const float* __restrict__ W2, const float* __restrict__ b2,
              float* __restrict__ q) {
  __shared__ float sW1h[F_DIM * 64];     // 32 KB — one column-half of W1
  __shared__ float sW2[F_DIM * D_DIM];   // 16 KB
  __shared__ float sB1[F_DIM];
  __shared__ float sB2[D_DIM];
  __shared__ float sX[8][F_DIM];         // 4 KB, wave-private rows
  __shared__ float sH[8][F_DIM];         // 4 KB, wave-private rows

  const int t = threadIdx.x;
  for (int i = t; i < F_DIM * D_DIM; i += 512) sW2[i] = W2[i];
  if (t < F_DIM) sB1[t] = b1[t];
  if (t >= 128 && t < 128 + D_DIM) sB2[t - 128] = b2[t - 128];

  const int wave = t >> 6;
  const int lane = t & 63;
  const int step = gridDim.x * 8;

  for (int base = blockIdx.x * 8; base < N_NODES; base += step) {
    const int row = base + wave;
    const bool active = row < N_NODES;

    if (active) {
      sX[wave][lane]      = x[(size_t)row * F_DIM + lane];
      sX[wave][lane + 64] = x[(size_t)row * F_DIM + lane + 64];
    }

#pragma unroll
    for (int half = 0; half < 2; ++half) {
      __syncthreads();  // all waves done reading previous sW1h contents
      // stage W1[:, half*64 : half*64+64] -> sW1h[k*64 + c]
      for (int i = t; i < F_DIM * 64; i += 512) {
        const int k = i >> 6;
        const int c = i & 63;
        sW1h[i] = W1[k * F_DIM + half * 64 + c];
      }
      __syncthreads();  // staging complete

      if (active) {
        const int col = half * 64 + lane;
        float h = sB1[col];
#pragma unroll 8
        for (int k = 0; k < F_DIM; ++k) {
          h += sX[wave][k] * sW1h[k * 64 + lane];
        }
        sH[wave][col] = swishf(h);
      }
    }

    if (active && lane < D_DIM) {
      float acc = sB2[lane];
#pragma unroll 8
      for (int j = 0; j < F_DIM; ++j) {
        acc += sH[wave][j] * sW2[j * D_DIM + lane];
      }
      q[(size_t)row * D_DIM + lane] = swishf(acc);
    }
  }
}

// ---------------------------------------------------------------------------
// Edge scatter: thread per (edge, d). 6 f32 atomicAdds per thread.
// ---------------------------------------------------------------------------
__global__ __launch_bounds__(256)
void edge_scatter(const float* __restrict__ rij, const float* __restrict__ vij,
                  const int* __restrict__ src, const int* __restrict__ dst,
                  const float* __restrict__ q, const float* __restrict__ q2,
                  float* __restrict__ mu, float* __restrict__ mu2) {
  const int tid = blockIdx.x * 256 + threadIdx.x;   // E*32 = 25.6M, fits int
  const int e = tid >> 5;
  const int d = tid & 31;
  if (e >= E_EDGES) return;

  const int s = src[e];
  const int t = dst[e];
  const float r = rij[e];
  float c = 0.0f;
  if (r < CUTOFF) c = 0.5f * (cosf(r * (3.14159265358979f / CUTOFF)) + 1.0f);

  const float vx = vij[3 * e + 0];
  const float vy = vij[3 * e + 1];
  const float vz = vij[3 * e + 2];

  const float a1 = q [(size_t)s * D_DIM + d] * c;
  const float a2 = q2[(size_t)s * D_DIM + d] * c;

  const size_t base = ((size_t)t * D_DIM + d) * 3;
  atomicAdd(&mu [base + 0], a1 * vx);
  atomicAdd(&mu [base + 1], a1 * vy);
  atomicAdd(&mu [base + 2], a1 * vz);
  atomicAdd(&mu2[base + 0], a2 * vx);
  atomicAdd(&mu2[base + 1], a2 * vy);
  atomicAdd(&mu2[base + 2], a2 * vz);
}

// ---------------------------------------------------------------------------
// Finalize: cross(mu, mu2) + Dense(3,1) mix -> out [N,D,3] f32
// ---------------------------------------------------------------------------
__global__ __launch_bounds__(256)
void finalize(const float* __restrict__ mu, const float* __restrict__ mu2,
              const float* __restrict__ w_mix, const float* __restrict__ b_mix,
              float* __restrict__ out) {
  const int i = blockIdx.x * 256 + threadIdx.x;  // per (n,d)
  if (i >= N_NODES * D_DIM) return;

  const float w0 = w_mix[0], w1 = w_mix[1], w2 = w_mix[2];
  const float bm = b_mix[0];

  const size_t base = (size_t)i * 3;
  const float ax = mu [base + 0], ay = mu [base + 1], az = mu [base + 2];
  const float bx = mu2[base + 0], by = mu2[base + 1], bz = mu2[base + 2];

  const float cx = ay * bz - az * by;
  const float cy = az * bx - ax * bz;
  const float cz = ax * by - ay * bx;

  out[base + 0] = ax * w0 + bx * w1 + cx * w2 + bm;
  out[base + 1] = ay * w0 + by * w1 + cy * w2 + bm;
  out[base + 2] = az * w0 + bz * w1 + cz * w2 + bm;
}

// ---------------------------------------------------------------------------
extern "C" void kernel_launch(void* const* d_in, const int* in_sizes, int n_in,
                              void* d_out, int out_size, void* d_ws, size_t ws_size,
                              hipStream_t stream) {
  const float* x     = (const float*)d_in[0];
  const float* rij   = (const float*)d_in[1];
  const float* vij   = (const float*)d_in[2];
  const int*   src   = (const int*)  d_in[3];
  const int*   dst   = (const int*)  d_in[4];
  const float* W1    = (const float*)d_in[5];
  const float* b1    = (const float*)d_in[6];
  const float* W2    = (const float*)d_in[7];
  const float* b2    = (const float*)d_in[8];
  const float* W1b   = (const float*)d_in[9];
  const float* b1b   = (const float*)d_in[10];
  const float* W2b   = (const float*)d_in[11];
  const float* b2b   = (const float*)d_in[12];
  const float* w_mix = (const float*)d_in[13];
  const float* b_mix = (const float*)d_in[14];
  float* out = (float*)d_out;

  // Workspace layout (f32): q [N*32] | q2 [N*32] | mu [N*32*3] | mu2 [N*32*3]
  float* q   = (float*)d_ws;
  float* q2  = q  + (size_t)N_NODES * D_DIM;
  float* mu  = q2 + (size_t)N_NODES * D_DIM;
  float* mu2 = mu + (size_t)N_NODES * D_DIM * 3;

  // ws is poisoned 0xAA before every timed launch -> zero the accumulators.
  hipMemsetAsync(mu, 0, sizeof(float) * (size_t)N_NODES * D_DIM * 3 * 2, stream);

  node_mlp<<<256, 512, 0, stream>>>(x, W1,  b1,  W2,  b2,  q);
  node_mlp<<<256, 512, 0, stream>>>(x, W1b, b1b, W2b, b2b, q2);

  const int total = E_EDGES * 32;
  edge_scatter<<<total / 256, 256, 0, stream>>>(rij, vij, src, dst, q, q2, mu, mu2);

  const int nd = N_NODES * D_DIM;
  finalize<<<(nd + 255) / 256, 256, 0, stream>>>(mu, mu2, w_mix, b_mix, out);
}

// Round 3
// 541.633 us; speedup vs baseline: 3.7172x; 3.7172x over previous
//
#include <hip/hip_runtime.h>
#include <hip/hip_bf16.h>

#define N_NODES 50000
#define E_EDGES 800000
#define F_DIM 128
#define D_DIM 32
#define CUTOFF 5.0f
#define PI_F 3.14159265358979f

__device__ __forceinline__ float swishf(float x) { return x / (1.0f + expf(-x)); }

// ---------------------------------------------------------------------------
// Node MLP v2: q = swish(swish(x@W1+b1)@W2+b2).
// Block = 512 (8 waves), each block does exactly 16 rows (grid 3125).
// Per wave: 2 rows. W1 staged per 64-col half (32 KB), W2 resident (16 KB),
// x rows per-wave in LDS (float4 reads); h overlays x after layer 1.
// LDS = 56 KB -> 2 blocks/CU.
// ---------------------------------------------------------------------------
__global__ __launch_bounds__(512)
void node_mlp(const float* __restrict__ x,
              const float* __restrict__ W1, const float* __restrict__ b1,
              const float* __restrict__ W2, const float* __restrict__ b2,
              float* __restrict__ q) {
  __shared__ float sW1h[F_DIM * 64];     // [k][c], c = col within current half
  __shared__ float sW2[F_DIM * D_DIM];   // [k][c]
  __shared__ float sXH[8][2][F_DIM];     // per-wave 2 rows: x, then h (overlay)

  const int t = threadIdx.x;
  const int w = t >> 6, l = t & 63;

  // stage W2 once (vectorized)
  {
    const float4* s4 = (const float4*)W2;
    float4* d4 = (float4*)sW2;
    for (int i = t; i < F_DIM * D_DIM / 4; i += 512) d4[i] = s4[i];
  }
  const float rb1a = b1[l];
  const float rb1b = b1[64 + l];
  const float rb2  = b2[l & 31];

  const int r0 = blockIdx.x * 16 + w * 2;   // 3125*16 = 50000 exactly

  // stage this wave's 2 x-rows (wave-private region, no barrier needed yet)
  {
    const int row = l >> 5;
    const int off = (l & 31) * 4;
    *((float4*)&sXH[w][row][off]) =
        *((const float4*)&x[(size_t)(r0 + row) * F_DIM + off]);
  }

  float h[4];  // [half*2 + row]: cols l (half0) and 64+l (half1), rows r0,r0+1

#pragma unroll
  for (int half = 0; half < 2; ++half) {
    __syncthreads();  // all waves done with previous sW1h contents (and W2/x staged)
    // stage W1[:, half*64 .. half*64+64) -> sW1h[k*64 + c], float4 chunks
    for (int i4 = t; i4 < 2048; i4 += 512) {
      const int k  = i4 >> 4;
      const int c4 = (i4 & 15) * 4;
      *((float4*)&sW1h[k * 64 + c4]) =
          *((const float4*)&W1[(size_t)k * F_DIM + half * 64 + c4]);
    }
    __syncthreads();

    float acc0 = (half == 0) ? rb1a : rb1b;
    float acc1 = acc0;
    const float4* xr0 = (const float4*)&sXH[w][0][0];
    const float4* xr1 = (const float4*)&sXH[w][1][0];
#pragma unroll 8
    for (int k4 = 0; k4 < 32; ++k4) {
      const float4 xa = xr0[k4];
      const float4 xb = xr1[k4];
      const float w0 = sW1h[(k4 * 4 + 0) * 64 + l];
      const float w1 = sW1h[(k4 * 4 + 1) * 64 + l];
      const float w2 = sW1h[(k4 * 4 + 2) * 64 + l];
      const float w3 = sW1h[(k4 * 4 + 3) * 64 + l];
      acc0 += xa.x * w0 + xa.y * w1 + xa.z * w2 + xa.w * w3;
      acc1 += xb.x * w0 + xb.y * w1 + xb.z * w2 + xb.w * w3;
    }
    h[half * 2 + 0] = swishf(acc0);
    h[half * 2 + 1] = swishf(acc1);
  }

  // overlay h onto the wave's x slot (x fully consumed)
  sXH[w][0][l]      = h[0];
  sXH[w][1][l]      = h[1];
  sXH[w][0][64 + l] = h[2];
  sXH[w][1][64 + l] = h[3];
  __syncthreads();  // drain LDS writes (cheap; removes in-wave ordering worry)

  // layer 2: group g = l/32 handles row r0+g, col c = l%32
  {
    const int g = l >> 5;
    const int c = l & 31;
    float acc = rb2;
    const float4* h4 = (const float4*)&sXH[w][g][0];
#pragma unroll 8
    for (int k4 = 0; k4 < 32; ++k4) {
      const float4 hv = h4[k4];
      acc += hv.x * sW2[(k4 * 4 + 0) * D_DIM + c]
           + hv.y * sW2[(k4 * 4 + 1) * D_DIM + c]
           + hv.z * sW2[(k4 * 4 + 2) * D_DIM + c]
           + hv.w * sW2[(k4 * 4 + 3) * D_DIM + c];
    }
    q[(size_t)(r0 + g) * D_DIM + c] = swishf(acc);
  }
}

// ---------------------------------------------------------------------------
// CSR build: histogram of dst over cutoff-surviving edges
// ---------------------------------------------------------------------------
__global__ __launch_bounds__(256)
void edge_hist(const float* __restrict__ rij, const int* __restrict__ dst,
               int* __restrict__ deg) {
  const int e = blockIdx.x * 256 + threadIdx.x;
  if (e >= E_EDGES) return;
  if (rij[e] < CUTOFF) atomicAdd(&deg[dst[e]], 1);
}

// Exclusive scan over deg[N] -> row_start[N+1] and cursor[N] (single block)
__global__ __launch_bounds__(1024)
void scan_offsets(const int* __restrict__ deg, int* __restrict__ row_start,
                  int* __restrict__ cursor) {
  __shared__ int part[1024];
  const int t = threadIdx.x;
  const int CH = (N_NODES + 1023) / 1024;  // 49
  const int lo = t * CH;
  const int hi = min(lo + CH, N_NODES);
  int s = 0;
  for (int i = lo; i < hi; ++i) s += deg[i];
  part[t] = s;
  __syncthreads();
  for (int off = 1; off < 1024; off <<= 1) {
    const int v = part[t];
    const int u = (t >= off) ? part[t - off] : 0;
    __syncthreads();
    part[t] = v + u;
    __syncthreads();
  }
  int excl = (t == 0) ? 0 : part[t - 1];
  for (int i = lo; i < hi; ++i) {
    row_start[i] = excl;
    cursor[i] = excl;
    excl += deg[i];
  }
  if (t == 1023) row_start[N_NODES] = part[1023];
}

// Reorder surviving edges into per-dst contiguous records:
// rec = (c*vx, c*vy, c*vz, bitcast(src))
__global__ __launch_bounds__(256)
void edge_reorder(const float* __restrict__ rij, const float* __restrict__ vij,
                  const int* __restrict__ src, const int* __restrict__ dst,
                  int* __restrict__ cursor, float4* __restrict__ recs) {
  const int e = blockIdx.x * 256 + threadIdx.x;
  if (e >= E_EDGES) return;
  const float r = rij[e];
  if (r >= CUTOFF) return;
  const float c = 0.5f * (cosf(r * (PI_F / CUTOFF)) + 1.0f);
  const int pos = atomicAdd(&cursor[dst[e]], 1);
  recs[pos] = make_float4(c * vij[3 * e + 0], c * vij[3 * e + 1],
                          c * vij[3 * e + 2], __int_as_float(src[e]));
}

// ---------------------------------------------------------------------------
// Gather + cross + mix: 32 lanes per node (one per d), registers only.
// ---------------------------------------------------------------------------
__global__ __launch_bounds__(256)
void gather_out(const int* __restrict__ row_start, const float4* __restrict__ recs,
                const float* __restrict__ q, const float* __restrict__ q2,
                const float* __restrict__ w_mix, const float* __restrict__ b_mix,
                float* __restrict__ out) {
  const int tid = blockIdx.x * 256 + threadIdx.x;  // = n*32 + d
  const int n = tid >> 5;
  const int d = tid & 31;
  if (n >= N_NODES) return;

  const int s0 = row_start[n];
  const int s1 = row_start[n + 1];

  float ax = 0.f, ay = 0.f, az = 0.f, bx = 0.f, by = 0.f, bz = 0.f;
  for (int i = s0; i < s1; ++i) {
    const float4 rc = recs[i];                 // broadcast across the 32 lanes
    const int s = __float_as_int(rc.w);
    const float qv  = q [s * D_DIM + d];       // coalesced 128 B line
    const float q2v = q2[s * D_DIM + d];
    ax += rc.x * qv;  ay += rc.y * qv;  az += rc.z * qv;
    bx += rc.x * q2v; by += rc.y * q2v; bz += rc.z * q2v;
  }

  const float cx = ay * bz - az * by;
  const float cy = az * bx - ax * bz;
  const float cz = ax * by - ay * bx;

  const float w0 = w_mix[0], w1 = w_mix[1], w2 = w_mix[2];
  const float bm = b_mix[0];

  const size_t base = (size_t)tid * 3;
  out[base + 0] = ax * w0 + bx * w1 + cx * w2 + bm;
  out[base + 1] = ay * w0 + by * w1 + cy * w2 + bm;
  out[base + 2] = az * w0 + bz * w1 + cz * w2 + bm;
}

// ---------------------------------------------------------------------------
extern "C" void kernel_launch(void* const* d_in, const int* in_sizes, int n_in,
                              void* d_out, int out_size, void* d_ws, size_t ws_size,
                              hipStream_t stream) {
  const float* x     = (const float*)d_in[0];
  const float* rij   = (const float*)d_in[1];
  const float* vij   = (const float*)d_in[2];
  const int*   src   = (const int*)  d_in[3];
  const int*   dst   = (const int*)  d_in[4];
  const float* W1    = (const float*)d_in[5];
  const float* b1    = (const float*)d_in[6];
  const float* W2    = (const float*)d_in[7];
  const float* b2    = (const float*)d_in[8];
  const float* W1b   = (const float*)d_in[9];
  const float* b1b   = (const float*)d_in[10];
  const float* W2b   = (const float*)d_in[11];
  const float* b2b   = (const float*)d_in[12];
  const float* w_mix = (const float*)d_in[13];
  const float* b_mix = (const float*)d_in[14];
  float* out = (float*)d_out;

  // Workspace (recs first for 16B alignment):
  // recs [E float4] | q [N*32] | q2 [N*32] | deg [N] | cursor [N] | row_start [N+1]
  float4* recs   = (float4*)d_ws;
  float* q       = (float*)(recs + E_EDGES);
  float* q2      = q + (size_t)N_NODES * D_DIM;
  int* deg       = (int*)(q2 + (size_t)N_NODES * D_DIM);
  int* cursor    = deg + N_NODES;
  int* row_start = cursor + N_NODES;

  hipMemsetAsync(deg, 0, sizeof(int) * N_NODES, stream);

  node_mlp<<<N_NODES / 16, 512, 0, stream>>>(x, W1,  b1,  W2,  b2,  q);
  node_mlp<<<N_NODES / 16, 512, 0, stream>>>(x, W1b, b1b, W2b, b2b, q2);

  const int eb = (E_EDGES + 255) / 256;
  edge_hist<<<eb, 256, 0, stream>>>(rij, dst, deg);
  scan_offsets<<<1, 1024, 0, stream>>>(deg, row_start, cursor);
  edge_reorder<<<eb, 256, 0, stream>>>(rij, vij, src, dst, cursor, recs);

  gather_out<<<(N_NODES * D_DIM) / 256, 256, 0, stream>>>(
      row_start, recs, q, q2, w_mix, b_mix, out);
}